// Round 1
// baseline (3444.621 us; speedup 1.0000x reference)
//
#include <hip/hip_runtime.h>

// UnMaxPoolWithArgmax: scatter-add unpool along H (stride 2).
// in:   (B, H, W, C) float32
// mask: (B, H, W, C) int (per-batch flat index into [2H, W, C])
// out:  (B, 2H, W, C) float32, duplicates summed (tf.scatter_nd semantics)

constexpr int Bb = 8;
constexpr int Hh = 512;
constexpr int Ww = 256;
constexpr int Cc = 64;
constexpr int WC = Ww * Cc;          // 16384 = 2^14
constexpr long long HWC = (long long)Hh * WC;   // 8,388,608
constexpr long long N_IN = (long long)Bb * HWC; // 67,108,864
constexpr long long OUT_PER_B = 2LL * HWC;      // 16,777,216

__global__ __launch_bounds__(256) void unmaxpool_scatter(
    const float* __restrict__ in, const int* __restrict__ mask,
    float* __restrict__ out)
{
    const long long n4 = N_IN / 4;
    long long g = (long long)blockIdx.x * blockDim.x + threadIdx.x;
    const long long stride = (long long)gridDim.x * blockDim.x;
    for (; g < n4; g += stride) {
        float4 v = reinterpret_cast<const float4*>(in)[g];
        int4   m = reinterpret_cast<const int4*>(mask)[g];
        long long i0 = g * 4;
        int b = (int)(i0 >> 23);            // i0 / HWC (HWC = 2^23)
        int c0 = (int)(i0 & (Cc - 1));      // input channel of elem 0
        long long obase = (long long)b * OUT_PER_B;

        // decode: y = m >> 14; x = (m & 16383) >> 6; keep input channel
        {
            int y = m.x >> 14, x = (m.x & (WC - 1)) >> 6;
            atomicAdd(&out[obase + ((long long)y << 14) + (x << 6) + (c0 + 0)], v.x);
        }
        {
            int y = m.y >> 14, x = (m.y & (WC - 1)) >> 6;
            atomicAdd(&out[obase + ((long long)y << 14) + (x << 6) + (c0 + 1)], v.y);
        }
        {
            int y = m.z >> 14, x = (m.z & (WC - 1)) >> 6;
            atomicAdd(&out[obase + ((long long)y << 14) + (x << 6) + (c0 + 2)], v.z);
        }
        {
            int y = m.w >> 14, x = (m.w & (WC - 1)) >> 6;
            atomicAdd(&out[obase + ((long long)y << 14) + (x << 6) + (c0 + 3)], v.w);
        }
    }
}

extern "C" void kernel_launch(void* const* d_in, const int* in_sizes, int n_in,
                              void* d_out, int out_size, void* d_ws, size_t ws_size,
                              hipStream_t stream) {
    const float* in   = (const float*)d_in[0];
    const int*   mask = (const int*)d_in[1];
    float*       out  = (float*)d_out;

    // Zero the output every call (deterministic; harness poisons 0xAA once).
    hipMemsetAsync(out, 0, (size_t)out_size * sizeof(float), stream);

    dim3 block(256);
    dim3 grid(2048);
    unmaxpool_scatter<<<grid, block, 0, stream>>>(in, mask, out);
}

// Round 2
// 1656.904 us; speedup vs baseline: 2.0790x; 2.0790x over previous
//
#include <hip/hip_runtime.h>

// UnMaxPoolWithArgmax via two-phase binning (no global atomics).
// in:   (B=8, H=512, W=256, C=64) f32 ; mask: same shape, int32 in [0, 2^24)
// out:  (8, 1024, 256, 64) f32, scatter-add semantics.
// target index = (b<<24) | (mask & ~63) | c   (27 bits)

typedef unsigned int u32;
typedef unsigned short u16;

constexpr long long N_IN  = 67108864LL;          // 8*512*256*64 = 2^26
constexpr int  RSH    = 15;                      // bucket region = 2^15 slots (128 KiB)
constexpr int  RSLOTS = 1 << RSH;                // 32768
constexpr int  NBCK   = 4096;                    // 2^27 / 2^15
constexpr int  TILE   = 1 << 17;                 // elements per phase-1 tile
constexpr int  NTILES = (int)(N_IN / TILE);      // 512
constexpr int  P1T    = 512;                     // phase-1 block size
constexpr int  P2T    = 1024;                    // phase-2 block size

// workspace layout
constexpr size_t OFF_VAL = 0;                                    // f32[N_IN]
constexpr size_t OFF_IDX = (size_t)N_IN * 4;                     // u16[N_IN]
constexpr size_t OFF_DIR = OFF_IDX + (size_t)N_IN * 2;           // u32[NTILES*NBCK]
constexpr size_t WS_NEED = OFF_DIR + (size_t)NTILES * NBCK * 4;  // ~392 MiB

__global__ __launch_bounds__(P1T) void p1_bin(const float* __restrict__ in,
                                              const int* __restrict__ mask,
                                              float* __restrict__ wval,
                                              u16* __restrict__ widx,
                                              u32* __restrict__ dir)
{
    __shared__ u32 hist[NBCK];      // histogram, then bucket cursors
    __shared__ u32 wsum[P1T / 64];
    const int tid  = threadIdx.x;
    const int lane = tid & 63;
    const int wid  = tid >> 6;
    const int t    = blockIdx.x;
    const int tilebase = t * TILE;        // < 2^26, fits int
    const int g4base   = tilebase >> 2;   // int4-group base

    for (int i = tid; i < NBCK; i += P1T) hist[i] = 0;
    __syncthreads();

    const int4*   m4 = (const int4*)mask;
    const float4* v4 = (const float4*)in;

    // ---- round A: bucket histogram (bucket ignores channel bits) ----
    for (int it = 0; it < TILE / 4 / P1T; ++it) {
        int gi = tid + it * P1T;
        int4 m = m4[g4base + gi];
        int  e0 = tilebase + gi * 4;
        u32  ob = ((u32)(e0 >> 23)) << 24;   // batch base (HWC = 2^23)
        atomicAdd(&hist[(ob + (u32)(m.x & ~63)) >> RSH], 1u);
        atomicAdd(&hist[(ob + (u32)(m.y & ~63)) >> RSH], 1u);
        atomicAdd(&hist[(ob + (u32)(m.z & ~63)) >> RSH], 1u);
        atomicAdd(&hist[(ob + (u32)(m.w & ~63)) >> RSH], 1u);
    }
    __syncthreads();

    // ---- block-wide exclusive scan of hist[4096] ----
    // each thread serially scans its 8 buckets; wave shfl-scan; thread-0 scan of wave sums
    u32 c[8];
    u32 run = 0;
    const int b0 = tid * (NBCK / P1T);   // 8 buckets per thread
#pragma unroll
    for (int j = 0; j < 8; ++j) { u32 x = hist[b0 + j]; c[j] = run; run += x; }
    u32 x = run;
#pragma unroll
    for (int d = 1; d < 64; d <<= 1) { u32 n = __shfl_up(x, (unsigned)d, 64); if (lane >= d) x += n; }
    if (lane == 63) wsum[wid] = x;
    u32 exwave = x - run;                // exclusive prefix of this thread within wave
    __syncthreads();
    if (tid == 0) {
        u32 r = 0;
        for (int w = 0; w < P1T / 64; ++w) { u32 s = wsum[w]; wsum[w] = r; r += s; }
    }
    __syncthreads();
    const u32 tbase = (u32)tilebase + wsum[wid] + exwave;
    // write directory (chunk bases) and init LDS cursors
#pragma unroll
    for (int j = 0; j < 8; ++j) {
        u32 bs = tbase + c[j];
        dir[t * NBCK + b0 + j] = bs;
        hist[b0 + j] = bs;               // safe: each thread touches only its own 8 slots
    }
    __syncthreads();

    // ---- round B: place (val, local idx) pairs ----
    for (int it = 0; it < TILE / 4 / P1T; ++it) {
        int gi = tid + it * P1T;
        int4   m = m4[g4base + gi];
        float4 v = v4[g4base + gi];
        int  e0 = tilebase + gi * 4;
        u32  ob = ((u32)(e0 >> 23)) << 24;
        u32  c0 = (u32)(e0 & 63);
        u32 tg, p;
        tg = ob + (u32)(m.x & ~63) + c0 + 0;
        p = atomicAdd(&hist[tg >> RSH], 1u);
        wval[p] = v.x; widx[p] = (u16)(tg & (RSLOTS - 1));
        tg = ob + (u32)(m.y & ~63) + c0 + 1;
        p = atomicAdd(&hist[tg >> RSH], 1u);
        wval[p] = v.y; widx[p] = (u16)(tg & (RSLOTS - 1));
        tg = ob + (u32)(m.z & ~63) + c0 + 2;
        p = atomicAdd(&hist[tg >> RSH], 1u);
        wval[p] = v.z; widx[p] = (u16)(tg & (RSLOTS - 1));
        tg = ob + (u32)(m.w & ~63) + c0 + 3;
        p = atomicAdd(&hist[tg >> RSH], 1u);
        wval[p] = v.w; widx[p] = (u16)(tg & (RSLOTS - 1));
    }
}

__global__ __launch_bounds__(P2T) void p2_acc(const float* __restrict__ wval,
                                              const u16* __restrict__ widx,
                                              const u32* __restrict__ dir,
                                              float* __restrict__ out)
{
    __shared__ float acc[RSLOTS];        // 128 KiB
    __shared__ u32 sbase[NTILES];        // 2 KiB
    __shared__ u32 send[NTILES];         // 2 KiB
    const int tid  = threadIdx.x;
    const int lane = tid & 63;
    const int wid  = tid >> 6;           // 0..15
    const int g    = blockIdx.x;

    for (int i = tid; i < RSLOTS; i += P2T) acc[i] = 0.f;
    if (tid < NTILES) {
        sbase[tid] = dir[tid * NBCK + g];
        send[tid]  = (g == NBCK - 1) ? (u32)((tid + 1) * TILE) : dir[tid * NBCK + g + 1];
    }
    __syncthreads();

    for (int t = wid; t < NTILES; t += P2T / 64) {
        u32 base = sbase[t];
        u32 end  = send[t];
        for (u32 k = base + (u32)lane; k < end; k += 64) {
            atomicAdd(&acc[widx[k]], wval[k]);
        }
    }
    __syncthreads();

    float4* out4 = (float4*)out;
    const float4* a4 = (const float4*)acc;
    const long long ob4 = (long long)g << (RSH - 2);   // g * 8192 float4s
    for (int i = tid; i < RSLOTS / 4; i += P2T) out4[ob4 + i] = a4[i];
}

// ---- fallback: direct atomic scatter (used only if ws too small) ----
__global__ __launch_bounds__(256) void unmaxpool_scatter(
    const float* __restrict__ in, const int* __restrict__ mask,
    float* __restrict__ out)
{
    const long long n4 = N_IN / 4;
    long long gidx = (long long)blockIdx.x * blockDim.x + threadIdx.x;
    const long long stride = (long long)gridDim.x * blockDim.x;
    for (; gidx < n4; gidx += stride) {
        float4 v = reinterpret_cast<const float4*>(in)[gidx];
        int4   m = reinterpret_cast<const int4*>(mask)[gidx];
        long long i0 = gidx * 4;
        u32 ob = ((u32)(i0 >> 23)) << 24;
        u32 c0 = (u32)(i0 & 63);
        atomicAdd(&out[ob + (u32)(m.x & ~63) + c0 + 0], v.x);
        atomicAdd(&out[ob + (u32)(m.y & ~63) + c0 + 1], v.y);
        atomicAdd(&out[ob + (u32)(m.z & ~63) + c0 + 2], v.z);
        atomicAdd(&out[ob + (u32)(m.w & ~63) + c0 + 3], v.w);
    }
}

extern "C" void kernel_launch(void* const* d_in, const int* in_sizes, int n_in,
                              void* d_out, int out_size, void* d_ws, size_t ws_size,
                              hipStream_t stream) {
    const float* in   = (const float*)d_in[0];
    const int*   mask = (const int*)d_in[1];
    float*       out  = (float*)d_out;

    if (ws_size >= WS_NEED && d_ws != nullptr) {
        char* ws = (char*)d_ws;
        float* wval = (float*)(ws + OFF_VAL);
        u16*   widx = (u16*)(ws + OFF_IDX);
        u32*   dir  = (u32*)(ws + OFF_DIR);
        p1_bin<<<NTILES, P1T, 0, stream>>>(in, mask, wval, widx, dir);
        p2_acc<<<NBCK, P2T, 0, stream>>>(wval, widx, dir, out);
    } else {
        hipMemsetAsync(out, 0, (size_t)out_size * sizeof(float), stream);
        unmaxpool_scatter<<<2048, 256, 0, stream>>>(in, mask, out);
    }
}